// Round 1
// baseline (154.877 us; speedup 1.0000x reference)
//
#include <hip/hip_runtime.h>
#include <stdint.h>

#define KTOT 400000

typedef __attribute__((ext_vector_type(8))) short sh8;
typedef __attribute__((ext_vector_type(4))) float f32x4;

typedef sh8      __attribute__((may_alias)) sh8_a;
typedef uint64_t __attribute__((may_alias)) u64_a;
typedef uint4    __attribute__((may_alias)) uint4_a;
typedef float4   __attribute__((may_alias)) float4_a;

// fp32 -> bf16 round-to-nearest-even (finite inputs)
__device__ __forceinline__ ushort f2bf(float f){
  union { float f; uint32_t u; } v; v.f = f;
  return (ushort)((v.u + 0x7FFFu + ((v.u >> 16) & 1u)) >> 16);
}

// Activation LDS tile: [4 row-tiles][16 batch][128 feat] bf16, XOR-swizzled.
// byte = ((rt*16+bi)*256 + feat*2) ^ ((bi&7)<<4)   (swizzle bits 4..6 only)
__device__ __forceinline__ int actoff(int rt, int bi, int kbyte){
  return (((rt << 4) + bi) << 8) + (kbyte ^ ((bi & 7) << 4));
}

// One dense layer for 64 rows (4 row-tiles of 16), in-place in the act tile.
// Weight frags are MFMA A-operand: A[i][k] = W[k][n0+i]  (i = lane&15 = out-feature,
// k = ks*32 + (lane>>4)*8 + j).  Act is B-operand: B[k][c] = act[batch c][k].
// D: lane holds batch = lane&15, out-features (lane>>4)*4 + 0..3  -> packed b64 writeback.
template<int KS, int NT, bool RELU>
__device__ __forceinline__ void layerf(const uint4* __restrict__ wf,
                                       const float* __restrict__ bp,
                                       char* actb, int lane)
{
  const int bi = lane & 15, g = lane >> 4;
  sh8 w[KS][NT];
  #pragma unroll
  for (int ks = 0; ks < KS; ks++)
    #pragma unroll
    for (int nt = 0; nt < NT; nt++)
      w[ks][nt] = __builtin_bit_cast(sh8, wf[(ks*NT + nt)*64 + lane]);

  float4 bv[NT];
  #pragma unroll
  for (int nt = 0; nt < NT; nt++)
    bv[nt] = *(const float4_a*)(bp + nt*16 + g*4);

  #pragma unroll
  for (int rt = 0; rt < 4; rt++){
    sh8 a[KS];
    #pragma unroll
    for (int ks = 0; ks < KS; ks++)
      a[ks] = *(const sh8_a*)(actb + actoff(rt, bi, ks*64 + g*16));

    f32x4 acc[NT];
    #pragma unroll
    for (int nt = 0; nt < NT; nt++)
      acc[nt] = (f32x4){bv[nt].x, bv[nt].y, bv[nt].z, bv[nt].w};  // bias as C-init

    #pragma unroll
    for (int ks = 0; ks < KS; ks++)
      #pragma unroll
      for (int nt = 0; nt < NT; nt++)
        acc[nt] = __builtin_amdgcn_mfma_f32_16x16x32_bf16(w[ks][nt], a[ks], acc[nt], 0, 0, 0);

    #pragma unroll
    for (int nt = 0; nt < NT; nt++){
      float x0 = acc[nt][0], x1 = acc[nt][1], x2 = acc[nt][2], x3 = acc[nt][3];
      if (RELU){ x0 = fmaxf(x0, 0.f); x1 = fmaxf(x1, 0.f);
                 x2 = fmaxf(x2, 0.f); x3 = fmaxf(x3, 0.f); }
      uint32_t lo = (uint32_t)f2bf(x0) | ((uint32_t)f2bf(x1) << 16);
      uint32_t hi = (uint32_t)f2bf(x2) | ((uint32_t)f2bf(x3) << 16);
      uint64_t pk = (uint64_t)lo | ((uint64_t)hi << 32);
      *(u64_a*)(actb + actoff(rt, bi, nt*32 + g*8)) = pk;  // 4 consecutive feats
    }
  }
  __syncthreads();
}

__global__ __launch_bounds__(64, 2)
void gnn_kernel(const float* __restrict__ data, const int* __restrict__ elements,
                const uint4* __restrict__ wf, const float* __restrict__ bp,
                float* __restrict__ out)
{
  __shared__ uint4 actsm[1024];            // 16 KB act tile
  __shared__ __align__(16) float fbuf[256];// 1 KB fp32 bounce for residual
  char* actb = (char*)actsm;
  const int lane = threadIdx.x;
  const int r0 = blockIdx.x * 64;

  // ---- gather: sent = [left.last, own 8, right.first], zero-pad k=10..31 ----
  #pragma unroll
  for (int rt = 0; rt < 4; rt++){
    if (lane < 16){
      int row = r0 + (rt << 4) + lane;
      int e = elements[row] / 9;                  // n_p + 1 = 9
      int le = (e == 0) ? KTOT - 1 : e - 1;
      int re = (e == KTOT - 1) ? 0 : e + 1;
      float lf = data[le*8 + 7];
      float4 d0 = *(const float4_a*)(data + e*8);
      float4 d1 = *(const float4_a*)(data + e*8 + 4);
      float rf = data[re*8];
      ushort s0=f2bf(lf),  s1=f2bf(d0.x), s2=f2bf(d0.y), s3=f2bf(d0.z), s4=f2bf(d0.w),
             s5=f2bf(d1.x), s6=f2bf(d1.y), s7=f2bf(d1.z), s8=f2bf(d1.w), s9=f2bf(rf);
      uint32_t p0 = s0 | ((uint32_t)s1 << 16), p1 = s2 | ((uint32_t)s3 << 16),
               p2 = s4 | ((uint32_t)s5 << 16), p3 = s6 | ((uint32_t)s7 << 16),
               p4 = s8 | ((uint32_t)s9 << 16);
      *(uint4_a*)(actb + actoff(rt, lane, 0 )) = make_uint4(p0, p1, p2, p3);
      *(uint4_a*)(actb + actoff(rt, lane, 16)) = make_uint4(p4, 0, 0, 0);
      *(uint4_a*)(actb + actoff(rt, lane, 32)) = make_uint4(0, 0, 0, 0);
      *(uint4_a*)(actb + actoff(rt, lane, 48)) = make_uint4(0, 0, 0, 0);
    }
  }
  __syncthreads();

  // ---- layers (frag offsets precomputed: 0,8,40,72,104,108,109) ----
  layerf<1, 8, true >(wf +   0*64, bp +   0, actb, lane);  // 10->128, relu
  layerf<4, 8, false>(wf +   8*64, bp + 128, actb, lane);  // 128->128
  layerf<4, 8, true >(wf +  40*64, bp + 256, actb, lane);  // 128->128, relu
  layerf<4, 8, false>(wf +  72*64, bp + 384, actb, lane);  // 128->128
  layerf<4, 1, true >(wf + 104*64, bp + 512, actb, lane);  // 128->8, relu (padded to 16)
  layerf<1, 1, false>(wf + 108*64, bp + 528, actb, lane);  // 8->8 (K padded to 32)

  // ---- final layer 8->10 + residual (keep f in fp32, coalesced epilogue) ----
  {
    const int bi = lane & 15, g = lane >> 4;
    sh8 w = __builtin_bit_cast(sh8, wf[109*64 + lane]);
    float4 bv = *(const float4_a*)(bp + 544 + g*4);
    #pragma unroll
    for (int rt = 0; rt < 4; rt++){
      sh8 a = *(const sh8_a*)(actb + actoff(rt, bi, g*16));
      f32x4 acc = (f32x4){bv.x, bv.y, bv.z, bv.w};
      acc = __builtin_amdgcn_mfma_f32_16x16x32_bf16(w, a, acc, 0, 0, 0);
      *(float4_a*)(&fbuf[bi*16 + g*4]) = make_float4(acc[0], acc[1], acc[2], acc[3]);
      __syncthreads();
      #pragma unroll
      for (int t = 0; t < 2; t++){
        int i = lane + t*64;
        int rr = i >> 3, c = i & 7;
        int row = r0 + (rt << 4) + rr;
        int e = elements[row] / 9;
        out[row*8 + c] = data[e*8 + c] + fbuf[rr*16 + c + 1];  // sent[:,1:-1] = own row
      }
      __syncthreads();
    }
  }
}

// ---- prep: pack weights into MFMA A-frag layout (bf16, zero-padded) + padded biases ----
// frag value: W_l[k*N + n], k = ks*32 + (lane>>4)*8 + j, n = nt*16 + (lane&15); 0 if OOB.
__global__ void prep_kernel(const float* __restrict__ W0, const float* __restrict__ b0,
                            const float* __restrict__ W1, const float* __restrict__ b1,
                            const float* __restrict__ W2, const float* __restrict__ b2,
                            const float* __restrict__ W3, const float* __restrict__ b3,
                            const float* __restrict__ W4, const float* __restrict__ b4,
                            const float* __restrict__ W5, const float* __restrict__ b5,
                            const float* __restrict__ W6, const float* __restrict__ b6,
                            uint4* __restrict__ wsfrag, float* __restrict__ biaspad)
{
  int tid = blockIdx.x * 256 + threadIdx.x;
  if (tid < 110*64){
    int frag = tid >> 6, lane = tid & 63;
    const int off[8] = {0, 8, 40, 72, 104, 108, 109, 110};
    const int Kd[7]  = {10, 128, 128, 128, 128, 8, 8};
    const int Nd[7]  = {128, 128, 128, 128, 8, 8, 10};
    const int NTt[7] = {8, 8, 8, 8, 1, 1, 1};
    int l = 0;
    while (frag >= off[l+1]) l++;
    int local = frag - off[l];
    int nt = local % NTt[l];
    int ks = local / NTt[l];
    const float* W = (l==0)?W0:(l==1)?W1:(l==2)?W2:(l==3)?W3:(l==4)?W4:(l==5)?W5:W6;
    int K = Kd[l], N = Nd[l];
    int n = nt*16 + (lane & 15);
    int kbase = ks*32 + ((lane >> 4) << 3);
    ushort us[8];
    #pragma unroll
    for (int j = 0; j < 8; j++){
      int k = kbase + j;
      float v = (k < K && n < N) ? W[k*N + n] : 0.f;
      us[j] = f2bf(v);
    }
    uint32_t p0 = (uint32_t)us[0] | ((uint32_t)us[1] << 16);
    uint32_t p1 = (uint32_t)us[2] | ((uint32_t)us[3] << 16);
    uint32_t p2 = (uint32_t)us[4] | ((uint32_t)us[5] << 16);
    uint32_t p3 = (uint32_t)us[6] | ((uint32_t)us[7] << 16);
    wsfrag[frag*64 + lane] = make_uint4(p0, p1, p2, p3);
  } else if (tid < 110*64 + 560){
    int i = tid - 110*64;
    float v;
    if (i < 512){                       // b0..b3, 128 each
      int l = i >> 7, idx = i & 127;
      const float* B = (l==0)?b0:(l==1)?b1:(l==2)?b2:b3;
      v = B[idx];
    } else {                            // b4..b6 padded to 16
      int j = i - 512;
      int l = j >> 4, idx = j & 15;
      const float* B = (l==0)?b4:(l==1)?b5:b6;
      int N = (l==2) ? 10 : 8;
      v = (idx < N) ? B[idx] : 0.f;
    }
    biaspad[i] = v;
  }
}

extern "C" void kernel_launch(void* const* d_in, const int* in_sizes, int n_in,
                              void* d_out, int out_size, void* d_ws, size_t ws_size,
                              hipStream_t stream)
{
  const float* data     = (const float*)d_in[0];
  const int*   elements = (const int*)  d_in[1];
  const float* W[7]; const float* B[7];
  for (int i = 0; i < 7; i++){ W[i] = (const float*)d_in[2 + 2*i]; B[i] = (const float*)d_in[3 + 2*i]; }

  uint4* wf = (uint4*)d_ws;                       // 110 frags * 64 lanes * 16 B = 112640 B
  float* bp = (float*)((char*)d_ws + 110*64*16);  // 560 padded bias floats

  prep_kernel<<<30, 256, 0, stream>>>(W[0],B[0],W[1],B[1],W[2],B[2],W[3],B[3],
                                      W[4],B[4],W[5],B[5],W[6],B[6], wf, bp);
  gnn_kernel<<<KTOT/64, 64, 0, stream>>>(data, elements, wf, bp, (float*)d_out);
}

// Round 9
// 149.011 us; speedup vs baseline: 1.0394x; 1.0394x over previous
//
#include <hip/hip_runtime.h>
#include <hip/hip_bf16.h>
#include <stdint.h>

#define KTOT 400000

typedef __attribute__((ext_vector_type(8))) short sh8;
typedef __attribute__((ext_vector_type(4))) float f32x4;

typedef sh8      __attribute__((may_alias)) sh8_a;
typedef uint2    __attribute__((may_alias)) uint2_a;
typedef uint4    __attribute__((may_alias)) uint4_a;
typedef float4   __attribute__((may_alias)) float4_a;

// fp32 -> bf16 via the NATIVE cast (m240: compiler lowers to v_cvt_pk_bf16_f32
// and schedules it; hand-written asm was -37% and is the prime NaN suspect).
__device__ __forceinline__ ushort f2bf16(float f){
  return __builtin_bit_cast(ushort, __float2bfloat16(f));
}
__device__ __forceinline__ uint32_t pkbf(float lo, float hi){
  return (uint32_t)f2bf16(lo) | ((uint32_t)f2bf16(hi) << 16);
}

// Activation LDS tile: [4 row-tiles][16 batch][128 feat] bf16, XOR-swizzled.
// byte = ((rt*16+bi)*256 + feat*2) ^ ((bi&7)<<4)   (swizzle bits 4..6 only)
__device__ __forceinline__ int actoff(int rt, int bi, int kbyte){
  return (((rt << 4) + bi) << 8) + (kbyte ^ ((bi & 7) << 4));
}

// One dense layer for 64 rows (4 row-tiles of 16), in-place in the act tile.
// Weight frags: A[i][k] = W[k][n0+i]; act is B-operand; D: lane holds
// batch = lane&15, out-feats (lane>>4)*4+0..3 -> one packed 8B writeback.
// ZPAD: additionally zero feats 16..31 (for the following fused 8->10 layer).
template<int KS, int NT, bool RELU, bool ZPAD>
__device__ __forceinline__ void layerf(const uint4* __restrict__ wf,
                                       const float* __restrict__ bp,
                                       char* actb, int lane)
{
  const int bi = lane & 15, g = lane >> 4;
  sh8 w[KS][NT];
  #pragma unroll
  for (int ks = 0; ks < KS; ks++)
    #pragma unroll
    for (int nt = 0; nt < NT; nt++)
      w[ks][nt] = __builtin_bit_cast(sh8, wf[(ks*NT + nt)*64 + lane]);

  float4 bv[NT];
  #pragma unroll
  for (int nt = 0; nt < NT; nt++)
    bv[nt] = *(const float4_a*)(bp + nt*16 + g*4);

  #pragma unroll
  for (int rt = 0; rt < 4; rt++){
    sh8 a[KS];
    #pragma unroll
    for (int ks = 0; ks < KS; ks++)
      a[ks] = *(const sh8_a*)(actb + actoff(rt, bi, ks*64 + g*16));

    f32x4 acc[NT];
    #pragma unroll
    for (int nt = 0; nt < NT; nt++)
      acc[nt] = (f32x4){bv[nt].x, bv[nt].y, bv[nt].z, bv[nt].w};  // bias as C-init

    #pragma unroll
    for (int ks = 0; ks < KS; ks++)
      #pragma unroll
      for (int nt = 0; nt < NT; nt++)
        acc[nt] = __builtin_amdgcn_mfma_f32_16x16x32_bf16(w[ks][nt], a[ks], acc[nt], 0, 0, 0);

    #pragma unroll
    for (int nt = 0; nt < NT; nt++){
      float x0 = acc[nt][0], x1 = acc[nt][1], x2 = acc[nt][2], x3 = acc[nt][3];
      if (RELU){ x0 = fmaxf(x0, 0.f); x1 = fmaxf(x1, 0.f);
                 x2 = fmaxf(x2, 0.f); x3 = fmaxf(x3, 0.f); }
      uint32_t lo = pkbf(x0, x1), hi = pkbf(x2, x3);
      *(uint2_a*)(actb + actoff(rt, bi, nt*32 + g*8)) = make_uint2(lo, hi);
    }
    if (ZPAD)
      *(uint2_a*)(actb + actoff(rt, bi, 32 + g*8)) = make_uint2(0u, 0u);
  }
  __syncthreads();
}

__global__ __launch_bounds__(64, 2)
void gnn_kernel(const float* __restrict__ data, const int* __restrict__ elements,
                const uint4* __restrict__ wf, const float* __restrict__ bp,
                float* __restrict__ out)
{
  __shared__ uint4 actsm[1024];             // 16 KB act tile
  __shared__ __align__(16) float fbuf[256]; // 1 KB fp32 bounce (round-1-proven)
  char* actb = (char*)actsm;
  const int lane = threadIdx.x;
  const int r0 = blockIdx.x * 64;
  const int bi = lane & 15, g = lane >> 4;

  // ---- gather: one row per lane. sent = [left.last, own 8, right.first], pad to 32 ----
  {
    int row = r0 + lane;
    int e = elements[row] / 9;                  // n_p + 1 = 9
    int le = (e == 0) ? KTOT - 1 : e - 1;
    int re = (e == KTOT - 1) ? 0 : e + 1;
    float lf = data[le*8 + 7];
    float4 d0 = *(const float4_a*)(data + e*8);
    float4 d1 = *(const float4_a*)(data + e*8 + 4);
    float rf = data[re*8];
    uint32_t p0 = pkbf(lf,   d0.x), p1 = pkbf(d0.y, d0.z),
             p2 = pkbf(d0.w, d1.x), p3 = pkbf(d1.y, d1.z),
             p4 = pkbf(d1.w, rf);
    *(uint4_a*)(actb + actoff(g, bi, 0 )) = make_uint4(p0, p1, p2, p3);
    *(uint4_a*)(actb + actoff(g, bi, 16)) = make_uint4(p4, 0, 0, 0);
    *(uint4_a*)(actb + actoff(g, bi, 32)) = make_uint4(0, 0, 0, 0);
    *(uint4_a*)(actb + actoff(g, bi, 48)) = make_uint4(0, 0, 0, 0);
  }
  __syncthreads();

  // ---- layers (frag offsets: 0,8,40,72,104,108; W5@W6 pre-fused in prep) ----
  layerf<1, 8, true , false>(wf +   0*64, bp +   0, actb, lane);  // 10->128, relu
  layerf<4, 8, false, false>(wf +   8*64, bp + 128, actb, lane);  // 128->128
  layerf<4, 8, true , false>(wf +  40*64, bp + 256, actb, lane);  // 128->128, relu
  layerf<4, 8, false, false>(wf +  72*64, bp + 384, actb, lane);  // 128->128
  layerf<4, 1, true , true >(wf + 104*64, bp + 512, actb, lane);  // 128->8, relu (pad 16, zpad 16..31)

  // ---- fused (W5@W6): 8->10, + residual epilogue (round-1 structure) ----
  {
    sh8 w = __builtin_bit_cast(sh8, wf[108*64 + lane]);
    float4 bv = *(const float4_a*)(bp + 528 + g*4);
    #pragma unroll
    for (int rt = 0; rt < 4; rt++){
      sh8 a = *(const sh8_a*)(actb + actoff(rt, bi, g*16));  // feats 0..31 (16..31 zeroed)
      f32x4 acc = (f32x4){bv.x, bv.y, bv.z, bv.w};
      acc = __builtin_amdgcn_mfma_f32_16x16x32_bf16(w, a, acc, 0, 0, 0);
      *(float4_a*)(&fbuf[bi*16 + g*4]) = make_float4(acc[0], acc[1], acc[2], acc[3]);
      __syncthreads();
      #pragma unroll
      for (int t = 0; t < 2; t++){
        int i = lane + t*64;
        int rr = i >> 3, c = i & 7;
        int row = r0 + (rt << 4) + rr;
        int e = elements[row] / 9;
        out[row*8 + c] = data[e*8 + c] + fbuf[rr*16 + c + 1];  // sent[:,1:-1] = own row
      }
      __syncthreads();
    }
  }
}

// ---- prep: pack weights into MFMA A-frag layout (bf16, zero-padded), fuse W5@W6,
// and build padded biases. 109 frags + 544 bias floats.
__global__ void prep_kernel(const float* __restrict__ W0, const float* __restrict__ b0,
                            const float* __restrict__ W1, const float* __restrict__ b1,
                            const float* __restrict__ W2, const float* __restrict__ b2,
                            const float* __restrict__ W3, const float* __restrict__ b3,
                            const float* __restrict__ W4, const float* __restrict__ b4,
                            const float* __restrict__ W5, const float* __restrict__ b5,
                            const float* __restrict__ W6, const float* __restrict__ b6,
                            uint4* __restrict__ wsfrag, float* __restrict__ biaspad)
{
  int tid = blockIdx.x * 256 + threadIdx.x;
  if (tid < 109*64){
    int frag = tid >> 6, lane = tid & 63;
    const int off[7] = {0, 8, 40, 72, 104, 108, 109};
    const int Kd[6]  = {10, 128, 128, 128, 128, 8};
    const int Nd[6]  = {128, 128, 128, 128, 8, 10};   // Nd = real cols = row stride
    const int NTt[6] = {8, 8, 8, 8, 1, 1};
    int l = 0;
    while (frag >= off[l+1]) l++;
    int local = frag - off[l];
    int nt = local % NTt[l];
    int ks = local / NTt[l];
    const float* W = (l==0)?W0:(l==1)?W1:(l==2)?W2:(l==3)?W3:W4;
    int K = Kd[l], N = Nd[l];
    int n = nt*16 + (lane & 15);
    int kbase = ks*32 + ((lane >> 4) << 3);
    ushort us[8];
    #pragma unroll
    for (int j = 0; j < 8; j++){
      int k = kbase + j;
      float v = 0.f;
      if (l == 5){                       // fused W56 = W5 @ W6 (fp32)
        if (k < 8 && n < 10){
          float s = 0.f;
          #pragma unroll
          for (int m = 0; m < 8; m++) s += W5[k*8 + m] * W6[m*10 + n];
          v = s;
        }
      } else if (k < K && n < N){
        v = W[k*N + n];
      }
      us[j] = f2bf16(v);
    }
    uint32_t p0 = (uint32_t)us[0] | ((uint32_t)us[1] << 16);
    uint32_t p1 = (uint32_t)us[2] | ((uint32_t)us[3] << 16);
    uint32_t p2 = (uint32_t)us[4] | ((uint32_t)us[5] << 16);
    uint32_t p3 = (uint32_t)us[6] | ((uint32_t)us[7] << 16);
    wsfrag[frag*64 + lane] = make_uint4(p0, p1, p2, p3);
  } else if (tid < 109*64 + 544){
    int i = tid - 109*64;
    float v;
    if (i < 512){                        // b0..b3, 128 each
      int l = i >> 7, idx = i & 127;
      const float* B = (l==0)?b0:(l==1)?b1:(l==2)?b2:b3;
      v = B[idx];
    } else if (i < 528){                 // b4 padded to 16
      int idx = i - 512;
      v = (idx < 8) ? b4[idx] : 0.f;
    } else {                             // b56 = b5 @ W6 + b6, padded to 16
      int n = i - 528;
      v = 0.f;
      if (n < 10){
        float s = b6[n];
        #pragma unroll
        for (int m = 0; m < 8; m++) s += b5[m] * W6[m*10 + n];
        v = s;
      }
    }
    biaspad[i] = v;
  }
}

extern "C" void kernel_launch(void* const* d_in, const int* in_sizes, int n_in,
                              void* d_out, int out_size, void* d_ws, size_t ws_size,
                              hipStream_t stream)
{
  const float* data     = (const float*)d_in[0];
  const int*   elements = (const int*)  d_in[1];
  const float* W[7]; const float* B[7];
  for (int i = 0; i < 7; i++){ W[i] = (const float*)d_in[2 + 2*i]; B[i] = (const float*)d_in[3 + 2*i]; }

  uint4* wf = (uint4*)d_ws;                       // 109 frags * 64 lanes * 16 B
  float* bp = (float*)((char*)d_ws + 109*64*16);  // 544 padded bias floats

  prep_kernel<<<30, 256, 0, stream>>>(W[0],B[0],W[1],B[1],W[2],B[2],W[3],B[3],
                                      W[4],B[4],W[5],B[5],W[6],B[6], wf, bp);
  gnn_kernel<<<KTOT/64, 64, 0, stream>>>(data, elements, wf, bp, (float*)d_out);
}

// Round 10
// 148.898 us; speedup vs baseline: 1.0402x; 1.0008x over previous
//
#include <hip/hip_runtime.h>
#include <hip/hip_bf16.h>
#include <stdint.h>

#define KTOT 400000

typedef __attribute__((ext_vector_type(8))) short sh8;
typedef __attribute__((ext_vector_type(4))) float f32x4;

typedef sh8      __attribute__((may_alias)) sh8_a;
typedef uint2    __attribute__((may_alias)) uint2_a;
typedef uint4    __attribute__((may_alias)) uint4_a;
typedef float4   __attribute__((may_alias)) float4_a;
typedef float    __attribute__((may_alias)) float_a;

// fp32 -> bf16 via the NATIVE cast (m240: compiler lowers to v_cvt_pk_bf16_f32;
// hand-written asm was the round-2/7 NaN bug AND -37% slower).
__device__ __forceinline__ ushort f2bf16(float f){
  return __builtin_bit_cast(ushort, __float2bfloat16(f));
}
__device__ __forceinline__ uint32_t pkbf(float lo, float hi){
  return (uint32_t)f2bf16(lo) | ((uint32_t)f2bf16(hi) << 16);
}

// compiler-only ordering fence (blocks are single-wave; DS pipe is in-order
// per wave, so no hardware barrier is ever needed inside a block).
__device__ __forceinline__ void wavebar(){ asm volatile("" ::: "memory"); }

// Activation LDS tile: [4 row-tiles][16 batch][128 feat] bf16, XOR-swizzled.
// byte = ((rt*16+bi)*256 + feat*2) ^ ((bi&7)<<4)   (swizzle bits 4..6 only)
__device__ __forceinline__ int actoff(int rt, int bi, int kbyte){
  return (((rt << 4) + bi) << 8) + (kbyte ^ ((bi & 7) << 4));
}

// fp32 epilogue bounce, overlaid on dead act space: bytes 192..255 of each
// row (only feats 0..31 = bytes 0..127 are live at that point). c in floats.
__device__ __forceinline__ int fbyte(int rt, int r, int c){
  return (((rt << 4) + r) << 8) + 192 + ((c << 2) ^ ((r & 3) << 4));
}

// One dense layer for 64 rows (4 row-tiles of 16), in-place in the act tile.
// Weight frags: A[i][k] = W[k][n0+i]; act is B-operand; D: lane holds
// batch = lane&15, out-feats (lane>>4)*4+0..3 -> one packed 8B writeback.
// ZPAD: additionally zero feats 16..31 (for the following fused 8->10 layer).
// NO barrier at the end: same-wave LDS dependence (may_alias) orders it, and
// leaving it open lets the compiler hoist the NEXT layer's weight loads.
template<int KS, int NT, bool RELU, bool ZPAD>
__device__ __forceinline__ void layerf(const uint4* __restrict__ wf,
                                       const float* __restrict__ bp,
                                       char* actb, int lane)
{
  const int bi = lane & 15, g = lane >> 4;
  sh8 w[KS][NT];
  #pragma unroll
  for (int ks = 0; ks < KS; ks++)
    #pragma unroll
    for (int nt = 0; nt < NT; nt++)
      w[ks][nt] = __builtin_bit_cast(sh8, wf[(ks*NT + nt)*64 + lane]);

  float4 bv[NT];
  #pragma unroll
  for (int nt = 0; nt < NT; nt++)
    bv[nt] = *(const float4_a*)(bp + nt*16 + g*4);

  #pragma unroll
  for (int rt = 0; rt < 4; rt++){
    sh8 a[KS];
    #pragma unroll
    for (int ks = 0; ks < KS; ks++)
      a[ks] = *(const sh8_a*)(actb + actoff(rt, bi, ks*64 + g*16));

    f32x4 acc[NT];
    #pragma unroll
    for (int nt = 0; nt < NT; nt++)
      acc[nt] = (f32x4){bv[nt].x, bv[nt].y, bv[nt].z, bv[nt].w};  // bias as C-init

    #pragma unroll
    for (int ks = 0; ks < KS; ks++)
      #pragma unroll
      for (int nt = 0; nt < NT; nt++)
        acc[nt] = __builtin_amdgcn_mfma_f32_16x16x32_bf16(w[ks][nt], a[ks], acc[nt], 0, 0, 0);

    #pragma unroll
    for (int nt = 0; nt < NT; nt++){
      float x0 = acc[nt][0], x1 = acc[nt][1], x2 = acc[nt][2], x3 = acc[nt][3];
      if (RELU){ x0 = fmaxf(x0, 0.f); x1 = fmaxf(x1, 0.f);
                 x2 = fmaxf(x2, 0.f); x3 = fmaxf(x3, 0.f); }
      uint32_t lo = pkbf(x0, x1), hi = pkbf(x2, x3);
      *(uint2_a*)(actb + actoff(rt, bi, nt*32 + g*8)) = make_uint2(lo, hi);
    }
    if (ZPAD)
      *(uint2_a*)(actb + actoff(rt, bi, 32 + g*8)) = make_uint2(0u, 0u);
  }
}

__global__ __launch_bounds__(64, 2)
void gnn_kernel(const float* __restrict__ data, const int* __restrict__ elements,
                const uint4* __restrict__ wf, const float* __restrict__ bp,
                float* __restrict__ out)
{
  __shared__ uint4 actsm[1024];            // exactly 16 KB -> 10 blocks/CU
  char* actb = (char*)actsm;
  const int lane = threadIdx.x;
  const int r0 = blockIdx.x * 64;
  const int bi = lane & 15, g = lane >> 4;

  // ---- gather: one row per lane. sent = [left.last, own 8, right.first], pad to 32 ----
  {
    int row = r0 + lane;
    int e = elements[row] / 9;                  // n_p + 1 = 9
    int le = (e == 0) ? KTOT - 1 : e - 1;
    int re = (e == KTOT - 1) ? 0 : e + 1;
    float lf = data[le*8 + 7];
    float4 d0 = *(const float4_a*)(data + e*8);
    float4 d1 = *(const float4_a*)(data + e*8 + 4);
    float rf = data[re*8];
    uint32_t p0 = pkbf(lf,   d0.x), p1 = pkbf(d0.y, d0.z),
             p2 = pkbf(d0.w, d1.x), p3 = pkbf(d1.y, d1.z),
             p4 = pkbf(d1.w, rf);
    *(uint4_a*)(actb + actoff(g, bi, 0 )) = make_uint4(p0, p1, p2, p3);
    *(uint4_a*)(actb + actoff(g, bi, 16)) = make_uint4(p4, 0, 0, 0);
    *(uint4_a*)(actb + actoff(g, bi, 32)) = make_uint4(0, 0, 0, 0);
    *(uint4_a*)(actb + actoff(g, bi, 48)) = make_uint4(0, 0, 0, 0);
  }

  // ---- layers (frag offsets: 0,8,40,72,104,108; W5@W6 pre-fused in prep) ----
  layerf<1, 8, true , false>(wf +   0*64, bp +   0, actb, lane);  // 10->128, relu
  layerf<4, 8, false, false>(wf +   8*64, bp + 128, actb, lane);  // 128->128
  layerf<4, 8, true , false>(wf +  40*64, bp + 256, actb, lane);  // 128->128, relu
  layerf<4, 8, false, false>(wf +  72*64, bp + 384, actb, lane);  // 128->128
  layerf<4, 1, true , true >(wf + 104*64, bp + 512, actb, lane);  // 128->8, relu (pad 16, zpad 16..31)

  // ---- fused (W5@W6): 8->10, all 4 rt first, then one fence, then residual ----
  {
    sh8 w = __builtin_bit_cast(sh8, wf[108*64 + lane]);
    float4 bv = *(const float4_a*)(bp + 528 + g*4);
    f32x4 facc[4];
    #pragma unroll
    for (int rt = 0; rt < 4; rt++){
      sh8 a = *(const sh8_a*)(actb + actoff(rt, bi, g*16));  // feats 0..31 (16..31 zeroed)
      f32x4 c0 = (f32x4){bv.x, bv.y, bv.z, bv.w};
      facc[rt] = __builtin_amdgcn_mfma_f32_16x16x32_bf16(w, a, c0, 0, 0, 0);
    }
    #pragma unroll
    for (int rt = 0; rt < 4; rt++)
      *(float4_a*)(actb + fbyte(rt, bi, g*4)) =
          make_float4(facc[rt][0], facc[rt][1], facc[rt][2], facc[rt][3]);
    wavebar();
    #pragma unroll
    for (int t = 0; t < 8; t++){
      int i = lane + t*64;                 // 512 outputs total
      int rt = i >> 7, rr = (i >> 3) & 15, c = i & 7;
      int row = r0 + (rt << 4) + rr;
      int e = elements[row] / 9;
      out[row*8 + c] = data[e*8 + c] + *(const float_a*)(actb + fbyte(rt, rr, c + 1));
    }
  }
}

// ---- prep: pack weights into MFMA A-frag layout (bf16, zero-padded), fuse W5@W6,
// and build padded biases. 109 frags + 544 bias floats.
__global__ void prep_kernel(const float* __restrict__ W0, const float* __restrict__ b0,
                            const float* __restrict__ W1, const float* __restrict__ b1,
                            const float* __restrict__ W2, const float* __restrict__ b2,
                            const float* __restrict__ W3, const float* __restrict__ b3,
                            const float* __restrict__ W4, const float* __restrict__ b4,
                            const float* __restrict__ W5, const float* __restrict__ b5,
                            const float* __restrict__ W6, const float* __restrict__ b6,
                            uint4* __restrict__ wsfrag, float* __restrict__ biaspad)
{
  int tid = blockIdx.x * 256 + threadIdx.x;
  if (tid < 109*64){
    int frag = tid >> 6, lane = tid & 63;
    const int off[7] = {0, 8, 40, 72, 104, 108, 109};
    const int Kd[6]  = {10, 128, 128, 128, 128, 8};
    const int Nd[6]  = {128, 128, 128, 128, 8, 10};   // Nd = real cols = row stride
    const int NTt[6] = {8, 8, 8, 8, 1, 1};
    int l = 0;
    while (frag >= off[l+1]) l++;
    int local = frag - off[l];
    int nt = local % NTt[l];
    int ks = local / NTt[l];
    const float* W = (l==0)?W0:(l==1)?W1:(l==2)?W2:(l==3)?W3:W4;
    int K = Kd[l], N = Nd[l];
    int n = nt*16 + (lane & 15);
    int kbase = ks*32 + ((lane >> 4) << 3);
    ushort us[8];
    #pragma unroll
    for (int j = 0; j < 8; j++){
      int k = kbase + j;
      float v = 0.f;
      if (l == 5){                       // fused W56 = W5 @ W6 (fp32)
        if (k < 8 && n < 10){
          float s = 0.f;
          #pragma unroll
          for (int m = 0; m < 8; m++) s += W5[k*8 + m] * W6[m*10 + n];
          v = s;
        }
      } else if (k < K && n < N){
        v = W[k*N + n];
      }
      us[j] = f2bf16(v);
    }
    uint32_t p0 = (uint32_t)us[0] | ((uint32_t)us[1] << 16);
    uint32_t p1 = (uint32_t)us[2] | ((uint32_t)us[3] << 16);
    uint32_t p2 = (uint32_t)us[4] | ((uint32_t)us[5] << 16);
    uint32_t p3 = (uint32_t)us[6] | ((uint32_t)us[7] << 16);
    wsfrag[frag*64 + lane] = make_uint4(p0, p1, p2, p3);
  } else if (tid < 109*64 + 544){
    int i = tid - 109*64;
    float v;
    if (i < 512){                        // b0..b3, 128 each
      int l = i >> 7, idx = i & 127;
      const float* B = (l==0)?b0:(l==1)?b1:(l==2)?b2:b3;
      v = B[idx];
    } else if (i < 528){                 // b4 padded to 16
      int idx = i - 512;
      v = (idx < 8) ? b4[idx] : 0.f;
    } else {                             // b56 = b5 @ W6 + b6, padded to 16
      int n = i - 528;
      v = 0.f;
      if (n < 10){
        float s = b6[n];
        #pragma unroll
        for (int m = 0; m < 8; m++) s += b5[m] * W6[m*10 + n];
        v = s;
      }
    }
    biaspad[i] = v;
  }
}

extern "C" void kernel_launch(void* const* d_in, const int* in_sizes, int n_in,
                              void* d_out, int out_size, void* d_ws, size_t ws_size,
                              hipStream_t stream)
{
  const float* data     = (const float*)d_in[0];
  const int*   elements = (const int*)  d_in[1];
  const float* W[7]; const float* B[7];
  for (int i = 0; i < 7; i++){ W[i] = (const float*)d_in[2 + 2*i]; B[i] = (const float*)d_in[3 + 2*i]; }

  uint4* wf = (uint4*)d_ws;                       // 109 frags * 64 lanes * 16 B
  float* bp = (float*)((char*)d_ws + 109*64*16);  // 544 padded bias floats

  prep_kernel<<<30, 256, 0, stream>>>(W[0],B[0],W[1],B[1],W[2],B[2],W[3],B[3],
                                      W[4],B[4],W[5],B[5],W[6],B[6], wf, bp);
  gnn_kernel<<<KTOT/64, 64, 0, stream>>>(data, elements, wf, bp, (float*)d_out);
}